// Round 1
// baseline (605.397 us; speedup 1.0000x reference)
//
#include <hip/hip_runtime.h>

#define N_PY 512
#define IN_F 6
#define OUT_F 64
#define BN_EPS 1e-5

// ---------------------------------------------------------------------------
// ws layout:
//   [0, 216)    : 27 doubles  — moment accumulators: sum_x[6], sum_xx[21]
//   [512, 2048) : float Wp[64*6], float bp[64] — BN-folded linear params
// ---------------------------------------------------------------------------

__global__ void __launch_bounds__(256)
pfn_stats_kernel(const float* __restrict__ x, int n, double* __restrict__ acc) {
    int tid = blockIdx.x * blockDim.x + threadIdx.x;
    int stride = gridDim.x * blockDim.x;

    float sx[6];
    float sxx[21];
#pragma unroll
    for (int j = 0; j < 6; ++j) sx[j] = 0.f;
#pragma unroll
    for (int k = 0; k < 21; ++k) sxx[k] = 0.f;

    for (int p = tid; p < n; p += stride) {
        float v[6];
#pragma unroll
        for (int j = 0; j < 6; ++j) v[j] = x[p * 6 + j];
#pragma unroll
        for (int j = 0; j < 6; ++j) sx[j] += v[j];
        int k = 0;
#pragma unroll
        for (int i = 0; i < 6; ++i)
#pragma unroll
            for (int j = i; j < 6; ++j) { sxx[k] += v[i] * v[j]; ++k; }
    }

    // wave64 butterfly reduce
#pragma unroll
    for (int off = 32; off > 0; off >>= 1) {
#pragma unroll
        for (int j = 0; j < 6; ++j) sx[j] += __shfl_down(sx[j], off, 64);
#pragma unroll
        for (int k = 0; k < 21; ++k) sxx[k] += __shfl_down(sxx[k], off, 64);
    }

    if ((threadIdx.x & 63) == 0) {
#pragma unroll
        for (int j = 0; j < 6; ++j) atomicAdd(&acc[j], (double)sx[j]);
#pragma unroll
        for (int k = 0; k < 21; ++k) atomicAdd(&acc[6 + k], (double)sxx[k]);
    }
}

__global__ void pfn_finalize_kernel(const double* __restrict__ acc,
                                    const float* __restrict__ W,
                                    const float* __restrict__ b,
                                    const float* __restrict__ gamma,
                                    const float* __restrict__ beta,
                                    int n,
                                    float* __restrict__ Wp,
                                    float* __restrict__ bp) {
    int f = threadIdx.x;  // 64 threads
    double inv_n = 1.0 / (double)n;

    double mx[6];
#pragma unroll
    for (int j = 0; j < 6; ++j) mx[j] = acc[j] * inv_n;

    double C[6][6];
    {
        int k = 0;
        for (int i = 0; i < 6; ++i)
            for (int j = i; j < 6; ++j) {
                double e = acc[6 + k] * inv_n - mx[i] * mx[j];
                C[i][j] = e;
                C[j][i] = e;
                ++k;
            }
    }

    double w[6];
#pragma unroll
    for (int j = 0; j < 6; ++j) w[j] = (double)W[f * 6 + j];

    double mean_h = (double)b[f];
#pragma unroll
    for (int j = 0; j < 6; ++j) mean_h += w[j] * mx[j];

    double var_h = 0.0;
    for (int i = 0; i < 6; ++i) {
        double t = 0.0;
        for (int j = 0; j < 6; ++j) t += C[i][j] * w[j];
        var_h += w[i] * t;
    }

    double s = (double)gamma[f] / sqrt(var_h + BN_EPS);

#pragma unroll
    for (int j = 0; j < 6; ++j) Wp[f * 6 + j] = (float)(w[j] * s);
    bp[f] = (float)(((double)b[f] - mean_h) * s + (double)beta[f]);
}

__global__ void __launch_bounds__(256)
pfn_scatter_kernel(const float* __restrict__ x,
                   const int* __restrict__ idx,
                   const float* __restrict__ Wp,
                   const float* __restrict__ bp,
                   float* __restrict__ out,
                   int n) {
    const int lane = threadIdx.x & 63;

    // per-lane (per-feature) folded weights
    const float w0 = Wp[lane * 6 + 0];
    const float w1 = Wp[lane * 6 + 1];
    const float w2 = Wp[lane * 6 + 2];
    const float w3 = Wp[lane * 6 + 3];
    const float w4 = Wp[lane * 6 + 4];
    const float w5 = Wp[lane * 6 + 5];
    const float bb = bp[lane];

    int gw = (int)((blockIdx.x * blockDim.x + threadIdx.x) >> 6);
    gw = __builtin_amdgcn_readfirstlane(gw);  // wave-uniform point cursor
    const int nw = (int)((gridDim.x * blockDim.x) >> 6);

    for (int p = gw; p < n; p += nw) {
        // wave-uniform loads (broadcast / scalar path)
        const float x0 = x[p * 6 + 0];
        const float x1 = x[p * 6 + 1];
        const float x2 = x[p * 6 + 2];
        const float x3 = x[p * 6 + 3];
        const float x4 = x[p * 6 + 4];
        const float x5 = x[p * 6 + 5];
        const int i0 = idx[p * 2 + 0];
        const int i1 = idx[p * 2 + 1];

        float v = bb;
        v = fmaf(w0, x0, v);
        v = fmaf(w1, x1, v);
        v = fmaf(w2, x2, v);
        v = fmaf(w3, x3, v);
        v = fmaf(w4, x4, v);
        v = fmaf(w5, x5, v);
        v = fmaxf(v, 0.0f);

        const int cell = i0 * N_PY + i1;
        atomicAdd(&out[(size_t)cell * OUT_F + lane], v);  // coalesced 256B/wave
    }
}

extern "C" void kernel_launch(void* const* d_in, const int* in_sizes, int n_in,
                              void* d_out, int out_size, void* d_ws, size_t ws_size,
                              hipStream_t stream) {
    const float* x     = (const float*)d_in[0];
    const int*   idx   = (const int*)d_in[1];
    const float* W     = (const float*)d_in[2];
    const float* b     = (const float*)d_in[3];
    const float* gamma = (const float*)d_in[4];
    const float* beta  = (const float*)d_in[5];
    float* out = (float*)d_out;

    const int n = in_sizes[0] / IN_F;

    double* acc = (double*)d_ws;
    float*  Wp  = (float*)((char*)d_ws + 512);
    float*  bp  = Wp + OUT_F * IN_F;

    // zero accumulators + output (harness poisons with 0xAA, atomics need 0)
    hipMemsetAsync(d_ws, 0, 512, stream);
    hipMemsetAsync(d_out, 0, (size_t)out_size * sizeof(float), stream);

    pfn_stats_kernel<<<512, 256, 0, stream>>>(x, n, acc);
    pfn_finalize_kernel<<<1, 64, 0, stream>>>(acc, W, b, gamma, beta, n, Wp, bp);
    pfn_scatter_kernel<<<1024, 256, 0, stream>>>(x, idx, Wp, bp, out, n);
}

// Round 2
// 240.114 us; speedup vs baseline: 2.5213x; 2.5213x over previous
//
#include <hip/hip_runtime.h>

#define N_PY 512
#define IN_F 6
#define OUT_F 64
#define BN_EPS 1e-5

// ---------------------------------------------------------------------------
// ws layout:
//   [0, 108)    : 27 floats  — moment accumulators: sum_x[6], sum_xx[21]
//   [512, 2048) : float Wp[64*6], float bp[64] — BN-folded linear params
// ---------------------------------------------------------------------------

__global__ void __launch_bounds__(256)
pfn_stats_kernel(const float* __restrict__ x, int n, float* __restrict__ acc) {
    const int tid = blockIdx.x * blockDim.x + threadIdx.x;
    const int stride = gridDim.x * blockDim.x;
    const int npairs = n >> 1;

    float s[27];
#pragma unroll
    for (int k = 0; k < 27; ++k) s[k] = 0.f;

    // 2 points per iteration: 48 B = 3 aligned float4 loads
    for (int q = tid; q < npairs; q += stride) {
        const float4* base = (const float4*)(x + (size_t)q * 12);
        const float4 a = base[0];
        const float4 b4 = base[1];
        const float4 c4 = base[2];
        const float p0[6] = {a.x, a.y, a.z, a.w, b4.x, b4.y};
        const float p1[6] = {b4.z, b4.w, c4.x, c4.y, c4.z, c4.w};
#pragma unroll
        for (int j = 0; j < 6; ++j) s[j] += p0[j] + p1[j];
        int k = 6;
#pragma unroll
        for (int i = 0; i < 6; ++i)
#pragma unroll
            for (int j = i; j < 6; ++j) {
                s[k] += p0[i] * p0[j] + p1[i] * p1[j];
                ++k;
            }
    }
    if ((n & 1) && tid == 0) {
        const float* p = x + (size_t)(n - 1) * 6;
        float v[6];
#pragma unroll
        for (int j = 0; j < 6; ++j) v[j] = p[j];
#pragma unroll
        for (int j = 0; j < 6; ++j) s[j] += v[j];
        int k = 6;
#pragma unroll
        for (int i = 0; i < 6; ++i)
#pragma unroll
            for (int j = i; j < 6; ++j) { s[k] += v[i] * v[j]; ++k; }
    }

    // wave64 butterfly reduce
#pragma unroll
    for (int off = 32; off > 0; off >>= 1)
#pragma unroll
        for (int k = 0; k < 27; ++k) s[k] += __shfl_down(s[k], off, 64);

    // cross-wave reduce in LDS: 4 waves/block
    __shared__ float lds[4][27];
    const int wid = threadIdx.x >> 6;
    const int lane = threadIdx.x & 63;
    if (lane == 0)
#pragma unroll
        for (int k = 0; k < 27; ++k) lds[wid][k] = s[k];
    __syncthreads();

    // threads 0..26 each own one counter: sum 4 wave partials, one f32 atomic
    if (threadIdx.x < 27) {
        const int k = threadIdx.x;
        const float v = lds[0][k] + lds[1][k] + lds[2][k] + lds[3][k];
        atomicAdd(&acc[k], v);   // native f32 atomic, fire-and-forget
    }
}

__global__ void pfn_finalize_kernel(const float* __restrict__ acc,
                                    const float* __restrict__ W,
                                    const float* __restrict__ b,
                                    const float* __restrict__ gamma,
                                    const float* __restrict__ beta,
                                    int n,
                                    float* __restrict__ Wp,
                                    float* __restrict__ bp) {
    int f = threadIdx.x;  // 64 threads
    double inv_n = 1.0 / (double)n;

    double mx[6];
#pragma unroll
    for (int j = 0; j < 6; ++j) mx[j] = (double)acc[j] * inv_n;

    double C[6][6];
    {
        int k = 0;
        for (int i = 0; i < 6; ++i)
            for (int j = i; j < 6; ++j) {
                double e = (double)acc[6 + k] * inv_n - mx[i] * mx[j];
                C[i][j] = e;
                C[j][i] = e;
                ++k;
            }
    }

    double w[6];
#pragma unroll
    for (int j = 0; j < 6; ++j) w[j] = (double)W[f * 6 + j];

    double mean_h = (double)b[f];
#pragma unroll
    for (int j = 0; j < 6; ++j) mean_h += w[j] * mx[j];

    double var_h = 0.0;
    for (int i = 0; i < 6; ++i) {
        double t = 0.0;
        for (int j = 0; j < 6; ++j) t += C[i][j] * w[j];
        var_h += w[i] * t;
    }

    double s = (double)gamma[f] / sqrt(var_h + BN_EPS);

#pragma unroll
    for (int j = 0; j < 6; ++j) Wp[f * 6 + j] = (float)(w[j] * s);
    bp[f] = (float)(((double)b[f] - mean_h) * s + (double)beta[f]);
}

__global__ void __launch_bounds__(256)
pfn_scatter_kernel(const float* __restrict__ x,
                   const int* __restrict__ idx,
                   const float* __restrict__ Wp,
                   const float* __restrict__ bp,
                   float* __restrict__ out,
                   int n) {
    const int lane = threadIdx.x & 63;

    // per-lane (per-feature) folded weights
    const float w0 = Wp[lane * 6 + 0];
    const float w1 = Wp[lane * 6 + 1];
    const float w2 = Wp[lane * 6 + 2];
    const float w3 = Wp[lane * 6 + 3];
    const float w4 = Wp[lane * 6 + 4];
    const float w5 = Wp[lane * 6 + 5];
    const float bb = bp[lane];

    int gw = (int)((blockIdx.x * blockDim.x + threadIdx.x) >> 6);
    gw = __builtin_amdgcn_readfirstlane(gw);  // wave-uniform point cursor
    const int nw = (int)((gridDim.x * blockDim.x) >> 6);

    for (int p = gw; p < n; p += nw) {
        // wave-uniform loads (broadcast / scalar path)
        const float x0 = x[p * 6 + 0];
        const float x1 = x[p * 6 + 1];
        const float x2 = x[p * 6 + 2];
        const float x3 = x[p * 6 + 3];
        const float x4 = x[p * 6 + 4];
        const float x5 = x[p * 6 + 5];
        const int i0 = idx[p * 2 + 0];
        const int i1 = idx[p * 2 + 1];

        float v = bb;
        v = fmaf(w0, x0, v);
        v = fmaf(w1, x1, v);
        v = fmaf(w2, x2, v);
        v = fmaf(w3, x3, v);
        v = fmaf(w4, x4, v);
        v = fmaf(w5, x5, v);
        v = fmaxf(v, 0.0f);

        const int cell = i0 * N_PY + i1;
        atomicAdd(&out[(size_t)cell * OUT_F + lane], v);  // coalesced 256B/wave
    }
}

extern "C" void kernel_launch(void* const* d_in, const int* in_sizes, int n_in,
                              void* d_out, int out_size, void* d_ws, size_t ws_size,
                              hipStream_t stream) {
    const float* x     = (const float*)d_in[0];
    const int*   idx   = (const int*)d_in[1];
    const float* W     = (const float*)d_in[2];
    const float* b     = (const float*)d_in[3];
    const float* gamma = (const float*)d_in[4];
    const float* beta  = (const float*)d_in[5];
    float* out = (float*)d_out;

    const int n = in_sizes[0] / IN_F;

    float* acc = (float*)d_ws;
    float* Wp  = (float*)((char*)d_ws + 512);
    float* bp  = Wp + OUT_F * IN_F;

    // zero accumulators + output (harness poisons with 0xAA, atomics need 0)
    hipMemsetAsync(d_ws, 0, 512, stream);
    hipMemsetAsync(d_out, 0, (size_t)out_size * sizeof(float), stream);

    pfn_stats_kernel<<<512, 256, 0, stream>>>(x, n, acc);
    pfn_finalize_kernel<<<1, 64, 0, stream>>>(acc, W, b, gamma, beta, n, Wp, bp);
    pfn_scatter_kernel<<<2048, 256, 0, stream>>>(x, idx, Wp, bp, out, n);
}

// Round 3
// 173.673 us; speedup vs baseline: 3.4858x; 1.3826x over previous
//
#include <hip/hip_runtime.h>

#define N_PY 512
#define IN_F 6
#define OUT_F 64
#define N_CELLS (512 * 512)
#define BN_EPS 1e-5

// ---------------------------------------------------------------------------
// ws layout:
//   [0, 108)        : 27 floats — moment accumulators: sum_x[6], sum_xx[21]
//   [512, 2048)     : float Wp[64*6], float bp[64] — BN-folded linear params
//   [4096, +1MB)    : int head[N_CELLS]  — per-cell linked-list head (-1 = empty)
//   [4096+1MB, +4MB): int nxt[N_POINTS]  — per-point next pointer
// ---------------------------------------------------------------------------

__global__ void __launch_bounds__(256)
pfn_stats_kernel(const float* __restrict__ x, int n, float* __restrict__ acc) {
    const int tid = blockIdx.x * blockDim.x + threadIdx.x;
    const int stride = gridDim.x * blockDim.x;
    const int npairs = n >> 1;

    float s[27];
#pragma unroll
    for (int k = 0; k < 27; ++k) s[k] = 0.f;

    // 2 points per iteration: 48 B = 3 aligned float4 loads
    for (int q = tid; q < npairs; q += stride) {
        const float4* base = (const float4*)(x + (size_t)q * 12);
        const float4 a = base[0];
        const float4 b4 = base[1];
        const float4 c4 = base[2];
        const float p0[6] = {a.x, a.y, a.z, a.w, b4.x, b4.y};
        const float p1[6] = {b4.z, b4.w, c4.x, c4.y, c4.z, c4.w};
#pragma unroll
        for (int j = 0; j < 6; ++j) s[j] += p0[j] + p1[j];
        int k = 6;
#pragma unroll
        for (int i = 0; i < 6; ++i)
#pragma unroll
            for (int j = i; j < 6; ++j) {
                s[k] += p0[i] * p0[j] + p1[i] * p1[j];
                ++k;
            }
    }
    if ((n & 1) && tid == 0) {
        const float* p = x + (size_t)(n - 1) * 6;
        float v[6];
#pragma unroll
        for (int j = 0; j < 6; ++j) v[j] = p[j];
#pragma unroll
        for (int j = 0; j < 6; ++j) s[j] += v[j];
        int k = 6;
#pragma unroll
        for (int i = 0; i < 6; ++i)
#pragma unroll
            for (int j = i; j < 6; ++j) { s[k] += v[i] * v[j]; ++k; }
    }

#pragma unroll
    for (int off = 32; off > 0; off >>= 1)
#pragma unroll
        for (int k = 0; k < 27; ++k) s[k] += __shfl_down(s[k], off, 64);

    __shared__ float lds[4][27];
    const int wid = threadIdx.x >> 6;
    const int lane = threadIdx.x & 63;
    if (lane == 0)
#pragma unroll
        for (int k = 0; k < 27; ++k) lds[wid][k] = s[k];
    __syncthreads();

    if (threadIdx.x < 27) {
        const int k = threadIdx.x;
        const float v = lds[0][k] + lds[1][k] + lds[2][k] + lds[3][k];
        atomicAdd(&acc[k], v);   // native f32 atomic, one per block per counter
    }
}

__global__ void pfn_finalize_kernel(const float* __restrict__ acc,
                                    const float* __restrict__ W,
                                    const float* __restrict__ b,
                                    const float* __restrict__ gamma,
                                    const float* __restrict__ beta,
                                    int n,
                                    float* __restrict__ Wp,
                                    float* __restrict__ bp) {
    int f = threadIdx.x;  // 64 threads
    double inv_n = 1.0 / (double)n;

    double mx[6];
#pragma unroll
    for (int j = 0; j < 6; ++j) mx[j] = (double)acc[j] * inv_n;

    double C[6][6];
    {
        int k = 0;
        for (int i = 0; i < 6; ++i)
            for (int j = i; j < 6; ++j) {
                double e = (double)acc[6 + k] * inv_n - mx[i] * mx[j];
                C[i][j] = e;
                C[j][i] = e;
                ++k;
            }
    }

    double w[6];
#pragma unroll
    for (int j = 0; j < 6; ++j) w[j] = (double)W[f * 6 + j];

    double mean_h = (double)b[f];
#pragma unroll
    for (int j = 0; j < 6; ++j) mean_h += w[j] * mx[j];

    double var_h = 0.0;
    for (int i = 0; i < 6; ++i) {
        double t = 0.0;
        for (int j = 0; j < 6; ++j) t += C[i][j] * w[j];
        var_h += w[i] * t;
    }

    double s = (double)gamma[f] / sqrt(var_h + BN_EPS);

#pragma unroll
    for (int j = 0; j < 6; ++j) Wp[f * 6 + j] = (float)(w[j] * s);
    bp[f] = (float)(((double)b[f] - mean_h) * s + (double)beta[f]);
}

// one thread per point: push point onto its cell's linked list
__global__ void __launch_bounds__(256)
pfn_build_kernel(const int* __restrict__ idx, int n,
                 int* __restrict__ head, int* __restrict__ nxt) {
    const int p = blockIdx.x * blockDim.x + threadIdx.x;
    if (p >= n) return;
    const int2 ij = ((const int2*)idx)[p];       // coalesced 8B load
    const int cell = ij.x * N_PY + ij.y;
    nxt[p] = atomicExch(&head[cell], p);         // 1 MB head array: L2-resident
}

// one wave per cell: walk chain, accumulate ReLU(x@Wp^T + bp) in registers,
// single coalesced 256B plain store (no atomics, no output memset needed)
__global__ void __launch_bounds__(256)
pfn_output_kernel(const float* __restrict__ x,
                  const int* __restrict__ head,
                  const int* __restrict__ nxt,
                  const float* __restrict__ Wp,
                  const float* __restrict__ bp,
                  float* __restrict__ out) {
    const int lane = threadIdx.x & 63;
    const int cell = __builtin_amdgcn_readfirstlane(
        (int)((blockIdx.x * blockDim.x + threadIdx.x) >> 6));

    const float w0 = Wp[lane * 6 + 0];
    const float w1 = Wp[lane * 6 + 1];
    const float w2 = Wp[lane * 6 + 2];
    const float w3 = Wp[lane * 6 + 3];
    const float w4 = Wp[lane * 6 + 4];
    const float w5 = Wp[lane * 6 + 5];
    const float bb = bp[lane];

    float s = 0.f;
    int p = head[cell];
    while (p >= 0) {
        const float* xp = x + (size_t)p * 6;
        const int pn = nxt[p];        // issue chain load early
        const float x0 = xp[0];
        const float x1 = xp[1];
        const float x2 = xp[2];
        const float x3 = xp[3];
        const float x4 = xp[4];
        const float x5 = xp[5];
        float v = bb;
        v = fmaf(w0, x0, v);
        v = fmaf(w1, x1, v);
        v = fmaf(w2, x2, v);
        v = fmaf(w3, x3, v);
        v = fmaf(w4, x4, v);
        v = fmaf(w5, x5, v);
        s += fmaxf(v, 0.0f);
        p = pn;
    }
    out[(size_t)cell * OUT_F + lane] = s;   // coalesced 256B/wave
}

// ---- fallback (R2 path) if ws too small for the list buffers ----
__global__ void __launch_bounds__(256)
pfn_scatter_kernel(const float* __restrict__ x,
                   const int* __restrict__ idx,
                   const float* __restrict__ Wp,
                   const float* __restrict__ bp,
                   float* __restrict__ out,
                   int n) {
    const int lane = threadIdx.x & 63;
    const float w0 = Wp[lane * 6 + 0];
    const float w1 = Wp[lane * 6 + 1];
    const float w2 = Wp[lane * 6 + 2];
    const float w3 = Wp[lane * 6 + 3];
    const float w4 = Wp[lane * 6 + 4];
    const float w5 = Wp[lane * 6 + 5];
    const float bb = bp[lane];

    int gw = (int)((blockIdx.x * blockDim.x + threadIdx.x) >> 6);
    gw = __builtin_amdgcn_readfirstlane(gw);
    const int nw = (int)((gridDim.x * blockDim.x) >> 6);

    for (int p = gw; p < n; p += nw) {
        const float x0 = x[p * 6 + 0];
        const float x1 = x[p * 6 + 1];
        const float x2 = x[p * 6 + 2];
        const float x3 = x[p * 6 + 3];
        const float x4 = x[p * 6 + 4];
        const float x5 = x[p * 6 + 5];
        const int i0 = idx[p * 2 + 0];
        const int i1 = idx[p * 2 + 1];

        float v = bb;
        v = fmaf(w0, x0, v);
        v = fmaf(w1, x1, v);
        v = fmaf(w2, x2, v);
        v = fmaf(w3, x3, v);
        v = fmaf(w4, x4, v);
        v = fmaf(w5, x5, v);
        v = fmaxf(v, 0.0f);

        const int cell = i0 * N_PY + i1;
        atomicAdd(&out[(size_t)cell * OUT_F + lane], v);
    }
}

extern "C" void kernel_launch(void* const* d_in, const int* in_sizes, int n_in,
                              void* d_out, int out_size, void* d_ws, size_t ws_size,
                              hipStream_t stream) {
    const float* x     = (const float*)d_in[0];
    const int*   idx   = (const int*)d_in[1];
    const float* W     = (const float*)d_in[2];
    const float* b     = (const float*)d_in[3];
    const float* gamma = (const float*)d_in[4];
    const float* beta  = (const float*)d_in[5];
    float* out = (float*)d_out;

    const int n = in_sizes[0] / IN_F;

    float* acc = (float*)d_ws;
    float* Wp  = (float*)((char*)d_ws + 512);
    float* bp  = Wp + OUT_F * IN_F;
    int*   head = (int*)((char*)d_ws + 4096);
    int*   nxt  = head + N_CELLS;

    const size_t need = 4096 + (size_t)(N_CELLS + n) * sizeof(int);

    hipMemsetAsync(d_ws, 0, 512, stream);                 // zero moment accumulators
    pfn_stats_kernel<<<512, 256, 0, stream>>>(x, n, acc);
    pfn_finalize_kernel<<<1, 64, 0, stream>>>(acc, W, b, gamma, beta, n, Wp, bp);

    if (ws_size >= need) {
        // linked-list aggregation path: no output memset, no f32 atomics on out
        hipMemsetAsync(head, 0xFF, (size_t)N_CELLS * sizeof(int), stream);  // head = -1
        pfn_build_kernel<<<(n + 255) / 256, 256, 0, stream>>>(idx, n, head, nxt);
        pfn_output_kernel<<<N_CELLS / 4, 256, 0, stream>>>(x, head, nxt, Wp, bp, out);
    } else {
        hipMemsetAsync(d_out, 0, (size_t)out_size * sizeof(float), stream);
        pfn_scatter_kernel<<<2048, 256, 0, stream>>>(x, idx, Wp, bp, out, n);
    }
}